// Round 6
// baseline (631.134 us; speedup 1.0000x reference)
//
#include <hip/hip_runtime.h>
#include <hip/hip_bf16.h>

#define N_NODES 100000
#define N_EDGES 1000000
#define D 64

// ---- histogram: ONE packed 64-bit atomic per edge, 4 edges/thread --------
// bits [63:40] = edge count, bits [39:0] = fixed-point sum of (w + 8) * 2^20
// The atomic's RETURN gives this edge's rank within its dst row -> rank[]
// so the CSR fill needs NO atomics.
__global__ __launch_bounds__(256) void hist_kernel(
    const int* __restrict__ dst, const int* __restrict__ efeat,
    const float* __restrict__ edge_weight,
    unsigned long long* __restrict__ dc,
    unsigned char* __restrict__ rank) {
    int e0 = (blockIdx.x * 256 + threadIdx.x) * 4;
    if (e0 >= N_EDGES) return;                 // N_EDGES % 4 == 0
    int4 d4 = *(const int4*)(dst + e0);
    int4 t4 = *(const int4*)(efeat + e0);
    float w0 = edge_weight[t4.x - 1] * 10.0f;
    float w1 = edge_weight[t4.y - 1] * 10.0f;
    float w2 = edge_weight[t4.z - 1] * 10.0f;
    float w3 = edge_weight[t4.w - 1] * 10.0f;
    w0 = w0 > 0.0f ? w0 : 0.01f * w0;          // leaky_relu, slope 0.01
    w1 = w1 > 0.0f ? w1 : 0.01f * w1;
    w2 = w2 > 0.0f ? w2 : 0.01f * w2;
    w3 = w3 > 0.0f ? w3 : 0.01f * w3;
    unsigned long long f0 = (unsigned long long)__float2uint_rn((w0 + 8.0f) * 1048576.0f);
    unsigned long long f1 = (unsigned long long)__float2uint_rn((w1 + 8.0f) * 1048576.0f);
    unsigned long long f2 = (unsigned long long)__float2uint_rn((w2 + 8.0f) * 1048576.0f);
    unsigned long long f3 = (unsigned long long)__float2uint_rn((w3 + 8.0f) * 1048576.0f);
    unsigned long long o0 = atomicAdd(&dc[d4.x], (1ull << 40) | f0);
    unsigned long long o1 = atomicAdd(&dc[d4.y], (1ull << 40) | f1);
    unsigned long long o2 = atomicAdd(&dc[d4.z], (1ull << 40) | f2);
    unsigned long long o3 = atomicAdd(&dc[d4.w], (1ull << 40) | f3);
    uchar4 r;
    r.x = (unsigned char)(o0 >> 40);
    r.y = (unsigned char)(o1 >> 40);
    r.z = (unsigned char)(o2 >> 40);
    r.w = (unsigned char)(o3 >> 40);
    *(uchar4*)(rank + e0) = r;
}

// ---- fused: dc -> meta{row_start,cnt,norm}, CSR alloc, AND build g1 ------
__global__ __launch_bounds__(256) void alloc_prep_kernel(
    const unsigned long long* __restrict__ dc,
    const float* __restrict__ feats,
    int4* __restrict__ meta,
    int* __restrict__ total,
    __hip_bfloat16* __restrict__ g1) {
    __shared__ int lds[256];
    __shared__ float norm_s[256];
    __shared__ int base_s;
    const int tid = threadIdx.x;
    const int i = blockIdx.x * 256 + tid;
    int v = 0;
    float nv = 1.0f;
    if (i < N_NODES) {
        unsigned long long p = dc[i];
        v = (int)(p >> 40);
        float deg = (float)(p & ((1ull << 40) - 1)) * (1.0f / 1048576.0f)
                    - 8.0f * (float)v;
        deg = deg < 1.0f ? 1.0f : deg;
        nv = rsqrtf(deg);
    }
    norm_s[tid] = nv;
    lds[tid] = v;
    __syncthreads();
    for (int off = 1; off < 256; off <<= 1) {
        int add = (tid >= off) ? lds[tid - off] : 0;
        __syncthreads();
        lds[tid] += add;
        __syncthreads();
    }
    if (tid == 255) base_s = atomicAdd(total, lds[255]);
    __syncthreads();
    if (i < N_NODES) {
        int4 m;
        m.x = base_s + lds[tid] - v;       // row_start (block-excl + base)
        m.y = v;                           // cnt
        m.z = __float_as_int(nv);          // norm
        m.w = 0;
        meta[i] = m;
    }
    // ---- g1[n][k] = bf16(feats[n][k] * norm[n]) for this block's nodes ---
    const float4* f4 = (const float4*)feats;
    __hip_bfloat162* g1p = (__hip_bfloat162*)g1;
    const int base4 = blockIdx.x * 4096;   // 256 nodes * 16 float4/node
#pragma unroll
    for (int r = 0; r < 16; r++) {
        int li = r * 256 + tid;
        int gi = base4 + li;
        if (gi < N_NODES * 16) {
            float4 vv = f4[gi];
            float ns = norm_s[li >> 4];
            __hip_bfloat162 a, b;
            a.x = __float2bfloat16(vv.x * ns); a.y = __float2bfloat16(vv.y * ns);
            b.x = __float2bfloat16(vv.z * ns); b.y = __float2bfloat16(vv.w * ns);
            g1p[gi * 2]     = a;
            g1p[gi * 2 + 1] = b;
        }
    }
}

// ---- atomic-free CSR fill: pos = row_start[dst] + rank, 4 edges/thread ---
__global__ __launch_bounds__(256) void fill_kernel(
    const int* __restrict__ src, const int* __restrict__ dst,
    const unsigned char* __restrict__ rank,
    const int* __restrict__ meta_i,        // meta as int*, row_start at 4*d
    int* __restrict__ csr_src) {
    int e0 = (blockIdx.x * 256 + threadIdx.x) * 4;
    if (e0 >= N_EDGES) return;
    int4 d4 = *(const int4*)(dst + e0);
    uchar4 r4 = *(const uchar4*)(rank + e0);
    int4 s4 = *(const int4*)(src + e0);
    int p0 = meta_i[d4.x * 4] + r4.x;          // 4 independent random reads
    int p1 = meta_i[d4.y * 4] + r4.y;
    int p2 = meta_i[d4.z * 4] + r4.z;
    int p3 = meta_i[d4.w * 4] + r4.w;
    csr_src[p0] = s4.x;
    csr_src[p1] = s4.y;
    csr_src[p2] = s4.z;
    csr_src[p3] = s4.w;
}

// ---- plain GEMM for j=0: out[:,0:64] = feats @ W0 ----
__global__ __launch_bounds__(256) void gemm_kernel(
    const float* __restrict__ H,
    const float* __restrict__ W,
    float* __restrict__ out) {
    __shared__ float wt[D][D];
    __shared__ float ht[32][D];
    const int tid = threadIdx.x;
    const int node0 = blockIdx.x * 32;
    for (int i = tid; i < D * D; i += 256)
        ((float*)wt)[i] = W[i];
    for (int i = tid; i < 32 * D; i += 256) {
        int n = i >> 6;
        int k = i & 63;
        int node = node0 + n;
        ht[n][k] = (node < N_NODES) ? H[(size_t)node * D + k] : 0.0f;
    }
    __syncthreads();
    const int col = tid & 63;
    const int nb = tid >> 6;
    float acc[8];
#pragma unroll
    for (int r = 0; r < 8; r++) acc[r] = 0.0f;
    for (int k = 0; k < D; k++) {
        float wv = wt[k][col];
#pragma unroll
        for (int r = 0; r < 8; r++)
            acc[r] += ht[nb * 8 + r][k] * wv;
    }
#pragma unroll
    for (int r = 0; r < 8; r++) {
        int node = node0 + nb * 8 + r;
        if (node < N_NODES)
            out[(size_t)node * 192 + col] = acc[r];
    }
}

// ---- fused bf16 gather-sum + GEMM epilogue, pipelined persistent waves ---
// Round-3 shape + coalesced index load + 2-deep cross-node prefetch.
// CRITICAL EXEC-MASK RULE: __shfl (ds_bpermute) from an exec-off lane is
// UNDEFINED. All shfls here execute under WAVE-UNIFORM loop bounds (full
// 8-slot groups + one uniform-guarded remainder group); only the gathers
// are per-lane predicated. Lanes >= cnt hold a clamped valid index, so any
// shfl source 0..63 is defined.
template <int SAVE_G2>
__global__ __launch_bounds__(256, 8) void spmm_gemm(
    const __hip_bfloat16* __restrict__ G,
    const int4* __restrict__ meta,
    const int* __restrict__ csr_src,
    const float* __restrict__ W,
    __hip_bfloat16* __restrict__ g2,
    float* __restrict__ out, int col_off) {
    __shared__ float wt[D * D];               // wt[k*D + col]
    const int tid = threadIdx.x;
    for (int i = tid; i < D * D; i += 256) wt[i] = W[i];
    __syncthreads();                          // once per block

    const int wv = tid >> 6;
    const int lane = tid & 63;
    const int half = lane >> 5;               // edge parity
    const int fp = lane & 31;                 // feature-pair index
    const unsigned int* Gp = (const unsigned int*)G;   // row = 32 dwords
    const int stride = gridDim.x * 4;

    const int n0 = blockIdx.x * 4 + wv;
    if (n0 >= N_NODES) return;

    // pipeline prologue
    int4 m0 = meta[n0];
    int nn1 = n0 + stride;
    int4 m1 = meta[nn1 < N_NODES ? nn1 : n0];         // clamped; unused if OOB
    int idx0 = csr_src[m0.x + (lane < m0.y ? lane : 0)];

    for (int node = n0; node < N_NODES; node += stride) {
        // prefetches for the pipeline (fly under this node's gathers)
        int nn2 = node + 2 * stride;
        int4 m2 = meta[nn2 < N_NODES ? nn2 : node];
        int idx1 = csr_src[m1.x + (lane < m1.y ? lane : 0)];

        const int cnt = m0.y;
        const float nn = __int_as_float(m0.z);
        const int jmax = cnt < 64 ? cnt : 64;
        const int full = jmax & ~7;           // complete 8-slot groups

        float accx = 0.0f, accy = 0.0f;
        // main loop: UNIFORM bound -> exec full at every shfl
        for (int base = 0; base < full; base += 8) {
            int j0 = base + half;
            int s0 = __shfl(idx0, j0);
            int s1 = __shfl(idx0, j0 + 2);
            int s2 = __shfl(idx0, j0 + 4);
            int s3 = __shfl(idx0, j0 + 6);
            unsigned int p0 = Gp[(size_t)s0 * 32 + fp];
            unsigned int p1 = Gp[(size_t)s1 * 32 + fp];
            unsigned int p2 = Gp[(size_t)s2 * 32 + fp];
            unsigned int p3 = Gp[(size_t)s3 * 32 + fp];
            float x0 = __uint_as_float(p0 << 16) + __uint_as_float(p1 << 16);
            float x1 = __uint_as_float(p2 << 16) + __uint_as_float(p3 << 16);
            float y0 = __uint_as_float(p0 & 0xffff0000u) + __uint_as_float(p1 & 0xffff0000u);
            float y1 = __uint_as_float(p2 & 0xffff0000u) + __uint_as_float(p3 & 0xffff0000u);
            accx += x0 + x1;
            accy += y0 + y1;
        }
        // remainder group: condition is wave-UNIFORM, shfls at full exec;
        // only the gathers are per-lane predicated (no cross-lane inside).
        if (full < jmax) {
            int j0 = full + half;
            int s0 = __shfl(idx0, j0);
            int s1 = __shfl(idx0, j0 + 2);
            int s2 = __shfl(idx0, j0 + 4);
            int s3 = __shfl(idx0, j0 + 6);
            if (j0 < jmax) {
                unsigned int p = Gp[(size_t)s0 * 32 + fp];
                accx += __uint_as_float(p << 16);
                accy += __uint_as_float(p & 0xffff0000u);
            }
            if (j0 + 2 < jmax) {
                unsigned int p = Gp[(size_t)s1 * 32 + fp];
                accx += __uint_as_float(p << 16);
                accy += __uint_as_float(p & 0xffff0000u);
            }
            if (j0 + 4 < jmax) {
                unsigned int p = Gp[(size_t)s2 * 32 + fp];
                accx += __uint_as_float(p << 16);
                accy += __uint_as_float(p & 0xffff0000u);
            }
            if (j0 + 6 < jmax) {
                unsigned int p = Gp[(size_t)s3 * 32 + fp];
                accx += __uint_as_float(p << 16);
                accy += __uint_as_float(p & 0xffff0000u);
            }
        }
        // deg > 64 fallback (practically never): broadcast loads, NO shfl
        for (int j = 64 + half; j < cnt; j += 2) {
            unsigned int p = Gp[(size_t)csr_src[m0.x + j] * 32 + fp];
            accx += __uint_as_float(p << 16);
            accy += __uint_as_float(p & 0xffff0000u);
        }

        // combine halves: lane l and l^32 hold the same feature pair
        accx += __shfl_xor(accx, 32);
        accy += __shfl_xor(accy, 32);
        accx *= nn;                           // dst-side norm folded here
        accy *= nn;

        if (SAVE_G2 && half == 0) {
            __hip_bfloat162 hb;
            hb.x = __float2bfloat16(accx * nn);
            hb.y = __float2bfloat16(accy * nn);
            ((__hip_bfloat162*)g2)[(size_t)node * 32 + fp] = hb;
        }

        // epilogue: o[col] = sum_k h[k]*W[k][col]; h[2q],h[2q+1] from lane q
        float o0 = 0.0f, o1 = 0.0f;
#pragma unroll
        for (int q = 0; q < 32; q++) {
            float hx = __uint_as_float(
                __builtin_amdgcn_readlane(__float_as_uint(accx), q));
            float hy = __uint_as_float(
                __builtin_amdgcn_readlane(__float_as_uint(accy), q));
            o0 = fmaf(hx, wt[(2 * q) * D + lane], o0);
            o1 = fmaf(hy, wt[(2 * q + 1) * D + lane], o1);
        }
        out[(size_t)node * 192 + col_off + lane] = o0 + o1;

        // pipeline shift
        m0 = m1; m1 = m2; idx0 = idx1;
    }
}

extern "C" void kernel_launch(void* const* d_in, const int* in_sizes, int n_in,
                              void* d_out, int out_size, void* d_ws, size_t ws_size,
                              hipStream_t stream) {
    const float* feats = (const float*)d_in[0];
    const float* ew    = (const float*)d_in[1];
    const float* w0    = (const float*)d_in[2];
    const float* w1    = (const float*)d_in[3];
    const float* w2    = (const float*)d_in[4];
    const int* src   = (const int*)d_in[5];
    const int* dst   = (const int*)d_in[6];
    const int* efeat = (const int*)d_in[7];
    float* out = (float*)d_out;

    // ws layout (~32 MiB): dc[N] u64 (800000 B) | total (16 B) |
    // meta[N] int4 (1.6 MB) | csr_src[1M] (4 MB) | g1 (12.8 MB) | g2 (12.8 MB)
    // rank[1M u8] ALIASES g2: hist writes rank, fill reads it, then spmm<1>
    // overwrites g2 — strictly ordered on the stream.
    unsigned long long* dc = (unsigned long long*)d_ws;
    int* total     = (int*)(dc + N_NODES);
    int4* meta     = (int4*)((char*)total + 16);
    int* csr_src   = (int*)(meta + N_NODES);
    __hip_bfloat16* g1 = (__hip_bfloat16*)(csr_src + N_EDGES);
    __hip_bfloat16* g2 = g1 + (size_t)N_NODES * D;
    unsigned char* rank = (unsigned char*)g2;  // dead before spmm<1> runs

    // zero dc + total only (~800 KB)
    hipMemsetAsync(d_ws, 0, sizeof(unsigned long long) * N_NODES + 16, stream);

    hist_kernel<<<(N_EDGES / 4 + 255) / 256, 256, 0, stream>>>(
        dst, efeat, ew, dc, rank);
    alloc_prep_kernel<<<(N_NODES + 255) / 256, 256, 0, stream>>>(
        dc, feats, meta, total, g1);
    fill_kernel<<<(N_EDGES / 4 + 255) / 256, 256, 0, stream>>>(
        src, dst, rank, (const int*)meta, csr_src);
    gemm_kernel<<<(N_NODES + 31) / 32, 256, 0, stream>>>(feats, w0, out);

    // cols 64..127 = (norm ⊙ A g1) @ W1, saving g2 = bf16(norm² ⊙ A g1)
    spmm_gemm<1><<<4096, 256, 0, stream>>>(
        g1, meta, csr_src, w1, g2, out, 64);
    // cols 128..191 = (norm ⊙ A g2) @ W2
    spmm_gemm<0><<<4096, 256, 0, stream>>>(
        g2, meta, csr_src, w2, nullptr, out, 128);
}

// Round 7
// 372.612 us; speedup vs baseline: 1.6938x; 1.6938x over previous
//
#include <hip/hip_runtime.h>
#include <hip/hip_bf16.h>

#define N_NODES 100000
#define N_EDGES 1000000
#define D 64

// ---- histogram: ONE packed 64-bit atomic per edge, 4 edges/thread --------
// bits [63:40] = edge count, bits [39:0] = fixed-point sum of (w + 8) * 2^20
// The atomic's RETURN gives this edge's rank within its dst row -> rank[]
// so the CSR fill needs NO atomics.
__global__ __launch_bounds__(256) void hist_kernel(
    const int* __restrict__ dst, const int* __restrict__ efeat,
    const float* __restrict__ edge_weight,
    unsigned long long* __restrict__ dc,
    unsigned char* __restrict__ rank) {
    int e0 = (blockIdx.x * 256 + threadIdx.x) * 4;
    if (e0 >= N_EDGES) return;                 // N_EDGES % 4 == 0
    int4 d4 = *(const int4*)(dst + e0);
    int4 t4 = *(const int4*)(efeat + e0);
    float w0 = edge_weight[t4.x - 1] * 10.0f;
    float w1 = edge_weight[t4.y - 1] * 10.0f;
    float w2 = edge_weight[t4.z - 1] * 10.0f;
    float w3 = edge_weight[t4.w - 1] * 10.0f;
    w0 = w0 > 0.0f ? w0 : 0.01f * w0;          // leaky_relu, slope 0.01
    w1 = w1 > 0.0f ? w1 : 0.01f * w1;
    w2 = w2 > 0.0f ? w2 : 0.01f * w2;
    w3 = w3 > 0.0f ? w3 : 0.01f * w3;
    unsigned long long f0 = (unsigned long long)__float2uint_rn((w0 + 8.0f) * 1048576.0f);
    unsigned long long f1 = (unsigned long long)__float2uint_rn((w1 + 8.0f) * 1048576.0f);
    unsigned long long f2 = (unsigned long long)__float2uint_rn((w2 + 8.0f) * 1048576.0f);
    unsigned long long f3 = (unsigned long long)__float2uint_rn((w3 + 8.0f) * 1048576.0f);
    unsigned long long o0 = atomicAdd(&dc[d4.x], (1ull << 40) | f0);
    unsigned long long o1 = atomicAdd(&dc[d4.y], (1ull << 40) | f1);
    unsigned long long o2 = atomicAdd(&dc[d4.z], (1ull << 40) | f2);
    unsigned long long o3 = atomicAdd(&dc[d4.w], (1ull << 40) | f3);
    uchar4 r;
    r.x = (unsigned char)(o0 >> 40);
    r.y = (unsigned char)(o1 >> 40);
    r.z = (unsigned char)(o2 >> 40);
    r.w = (unsigned char)(o3 >> 40);
    *(uchar4*)(rank + e0) = r;
}

// ---- fused: dc -> meta{row_start,cnt,norm}, CSR alloc, AND build g1 ------
__global__ __launch_bounds__(256) void alloc_prep_kernel(
    const unsigned long long* __restrict__ dc,
    const float* __restrict__ feats,
    int4* __restrict__ meta,
    int* __restrict__ total,
    __hip_bfloat16* __restrict__ g1) {
    __shared__ int lds[256];
    __shared__ float norm_s[256];
    __shared__ int base_s;
    const int tid = threadIdx.x;
    const int i = blockIdx.x * 256 + tid;
    int v = 0;
    float nv = 1.0f;
    if (i < N_NODES) {
        unsigned long long p = dc[i];
        v = (int)(p >> 40);
        float deg = (float)(p & ((1ull << 40) - 1)) * (1.0f / 1048576.0f)
                    - 8.0f * (float)v;
        deg = deg < 1.0f ? 1.0f : deg;
        nv = rsqrtf(deg);
    }
    norm_s[tid] = nv;
    lds[tid] = v;
    __syncthreads();
    for (int off = 1; off < 256; off <<= 1) {
        int add = (tid >= off) ? lds[tid - off] : 0;
        __syncthreads();
        lds[tid] += add;
        __syncthreads();
    }
    if (tid == 255) base_s = atomicAdd(total, lds[255]);
    __syncthreads();
    if (i < N_NODES) {
        int4 m;
        m.x = base_s + lds[tid] - v;       // row_start (block-excl + base)
        m.y = v;                           // cnt
        m.z = __float_as_int(nv);          // norm
        m.w = 0;
        meta[i] = m;
    }
    // ---- g1[n][k] = bf16(feats[n][k] * norm[n]) for this block's nodes ---
    const float4* f4 = (const float4*)feats;
    __hip_bfloat162* g1p = (__hip_bfloat162*)g1;
    const int base4 = blockIdx.x * 4096;   // 256 nodes * 16 float4/node
#pragma unroll
    for (int r = 0; r < 16; r++) {
        int li = r * 256 + tid;
        int gi = base4 + li;
        if (gi < N_NODES * 16) {
            float4 vv = f4[gi];
            float ns = norm_s[li >> 4];
            __hip_bfloat162 a, b;
            a.x = __float2bfloat16(vv.x * ns); a.y = __float2bfloat16(vv.y * ns);
            b.x = __float2bfloat16(vv.z * ns); b.y = __float2bfloat16(vv.w * ns);
            g1p[gi * 2]     = a;
            g1p[gi * 2 + 1] = b;
        }
    }
}

// ---- atomic-free CSR fill: pos = row_start[dst] + rank, 4 edges/thread ---
__global__ __launch_bounds__(256) void fill_kernel(
    const int* __restrict__ src, const int* __restrict__ dst,
    const unsigned char* __restrict__ rank,
    const int* __restrict__ meta_i,        // meta as int*, row_start at 4*d
    int* __restrict__ csr_src) {
    int e0 = (blockIdx.x * 256 + threadIdx.x) * 4;
    if (e0 >= N_EDGES) return;
    int4 d4 = *(const int4*)(dst + e0);
    uchar4 r4 = *(const uchar4*)(rank + e0);
    int4 s4 = *(const int4*)(src + e0);
    int p0 = meta_i[d4.x * 4] + r4.x;          // 4 independent random reads
    int p1 = meta_i[d4.y * 4] + r4.y;
    int p2 = meta_i[d4.z * 4] + r4.z;
    int p3 = meta_i[d4.w * 4] + r4.w;
    csr_src[p0] = s4.x;
    csr_src[p1] = s4.y;
    csr_src[p2] = s4.z;
    csr_src[p3] = s4.w;
}

// ---- plain GEMM for j=0: out[:,0:64] = feats @ W0 ----
__global__ __launch_bounds__(256) void gemm_kernel(
    const float* __restrict__ H,
    const float* __restrict__ W,
    float* __restrict__ out) {
    __shared__ float wt[D][D];
    __shared__ float ht[32][D];
    const int tid = threadIdx.x;
    const int node0 = blockIdx.x * 32;
    for (int i = tid; i < D * D; i += 256)
        ((float*)wt)[i] = W[i];
    for (int i = tid; i < 32 * D; i += 256) {
        int n = i >> 6;
        int k = i & 63;
        int node = node0 + n;
        ht[n][k] = (node < N_NODES) ? H[(size_t)node * D + k] : 0.0f;
    }
    __syncthreads();
    const int col = tid & 63;
    const int nb = tid >> 6;
    float acc[8];
#pragma unroll
    for (int r = 0; r < 8; r++) acc[r] = 0.0f;
    for (int k = 0; k < D; k++) {
        float wv = wt[k][col];
#pragma unroll
        for (int r = 0; r < 8; r++)
            acc[r] += ht[nb * 8 + r][k] * wv;
    }
#pragma unroll
    for (int r = 0; r < 8; r++) {
        int node = node0 + nb * 8 + r;
        if (node < N_NODES)
            out[(size_t)node * 192 + col] = acc[r];
    }
}

// ---- fused bf16 gather-sum + GEMM epilogue, persistent waves -------------
// PROVEN round-3 body (broadcast index loads, 2 accumulators, VGPR~48, no
// forced launch-bounds floor — round 6 showed __launch_bounds__(256,8)
// forces spills: VGPR 48->32 with MORE state, FETCH 103->635 MB of scratch
// traffic). Grid 4096 (2 scheduling rounds of blocks) is the one round-6
// ingredient that worked: backfill raised occupancy 39% -> 89%.
template <int SAVE_G2>
__global__ __launch_bounds__(256) void spmm_gemm(
    const __hip_bfloat16* __restrict__ G,
    const int4* __restrict__ meta,
    const int* __restrict__ csr_src,
    const float* __restrict__ W,
    __hip_bfloat16* __restrict__ g2,
    float* __restrict__ out, int col_off) {
    __shared__ float wt[D * D];               // wt[k*D + col]
    const int tid = threadIdx.x;
    for (int i = tid; i < D * D; i += 256) wt[i] = W[i];
    __syncthreads();                          // once per block

    const int wv = tid >> 6;
    const int lane = tid & 63;
    const int half = lane >> 5;               // edge parity
    const int fp = lane & 31;                 // feature-pair index
    const unsigned int* Gp = (const unsigned int*)G;   // row = 32 dwords
    const int stride = gridDim.x * 4;

    for (int node = blockIdx.x * 4 + wv; node < N_NODES; node += stride) {
        const int4 m = meta[node];
        const int beg = m.x;
        const int end = m.x + m.y;
        const float nn = __int_as_float(m.z);

        float accx = 0.0f, accy = 0.0f;
        int e = beg + half;                   // this half's first slot
        // main loop: 4 independent dword gathers (= 8 edges/wave) in flight
        for (; e + 6 < end; e += 8) {
            int s0 = csr_src[e];
            int s1 = csr_src[e + 2];
            int s2 = csr_src[e + 4];
            int s3 = csr_src[e + 6];
            unsigned int p0 = Gp[(size_t)s0 * 32 + fp];
            unsigned int p1 = Gp[(size_t)s1 * 32 + fp];
            unsigned int p2 = Gp[(size_t)s2 * 32 + fp];
            unsigned int p3 = Gp[(size_t)s3 * 32 + fp];
            float x0 = __uint_as_float(p0 << 16) + __uint_as_float(p1 << 16);
            float x1 = __uint_as_float(p2 << 16) + __uint_as_float(p3 << 16);
            float y0 = __uint_as_float(p0 & 0xffff0000u) + __uint_as_float(p1 & 0xffff0000u);
            float y1 = __uint_as_float(p2 & 0xffff0000u) + __uint_as_float(p3 & 0xffff0000u);
            accx += x0 + x1;
            accy += y0 + y1;
        }
        for (; e < end; e += 2) {             // tail (this half's parity)
            unsigned int p = Gp[(size_t)csr_src[e] * 32 + fp];
            accx += __uint_as_float(p << 16);
            accy += __uint_as_float(p & 0xffff0000u);
        }
        // combine halves: lane l and l^32 hold the same feature pair
        accx += __shfl_xor(accx, 32);
        accy += __shfl_xor(accy, 32);
        accx *= nn;                           // dst-side norm folded here
        accy *= nn;

        if (SAVE_G2 && half == 0) {
            __hip_bfloat162 hb;
            hb.x = __float2bfloat16(accx * nn);
            hb.y = __float2bfloat16(accy * nn);
            ((__hip_bfloat162*)g2)[(size_t)node * 32 + fp] = hb;
        }

        // epilogue: o[col] = sum_k h[k]*W[k][col]; h[2q],h[2q+1] from lane q
        float o0 = 0.0f, o1 = 0.0f;
#pragma unroll
        for (int q = 0; q < 32; q++) {
            float hx = __uint_as_float(
                __builtin_amdgcn_readlane(__float_as_uint(accx), q));
            float hy = __uint_as_float(
                __builtin_amdgcn_readlane(__float_as_uint(accy), q));
            o0 = fmaf(hx, wt[(2 * q) * D + lane], o0);
            o1 = fmaf(hy, wt[(2 * q + 1) * D + lane], o1);
        }
        out[(size_t)node * 192 + col_off + lane] = o0 + o1;
    }
}

extern "C" void kernel_launch(void* const* d_in, const int* in_sizes, int n_in,
                              void* d_out, int out_size, void* d_ws, size_t ws_size,
                              hipStream_t stream) {
    const float* feats = (const float*)d_in[0];
    const float* ew    = (const float*)d_in[1];
    const float* w0    = (const float*)d_in[2];
    const float* w1    = (const float*)d_in[3];
    const float* w2    = (const float*)d_in[4];
    const int* src   = (const int*)d_in[5];
    const int* dst   = (const int*)d_in[6];
    const int* efeat = (const int*)d_in[7];
    float* out = (float*)d_out;

    // ws layout (~32 MiB): dc[N] u64 (800000 B) | total (16 B) |
    // meta[N] int4 (1.6 MB) | csr_src[1M] (4 MB) | g1 (12.8 MB) | g2 (12.8 MB)
    // rank[1M u8] ALIASES g2: hist writes rank, fill reads it, then spmm<1>
    // overwrites g2 — strictly ordered on the stream.
    unsigned long long* dc = (unsigned long long*)d_ws;
    int* total     = (int*)(dc + N_NODES);
    int4* meta     = (int4*)((char*)total + 16);
    int* csr_src   = (int*)(meta + N_NODES);
    __hip_bfloat16* g1 = (__hip_bfloat16*)(csr_src + N_EDGES);
    __hip_bfloat16* g2 = g1 + (size_t)N_NODES * D;
    unsigned char* rank = (unsigned char*)g2;  // dead before spmm<1> runs

    // zero dc + total only (~800 KB)
    hipMemsetAsync(d_ws, 0, sizeof(unsigned long long) * N_NODES + 16, stream);

    hist_kernel<<<(N_EDGES / 4 + 255) / 256, 256, 0, stream>>>(
        dst, efeat, ew, dc, rank);
    alloc_prep_kernel<<<(N_NODES + 255) / 256, 256, 0, stream>>>(
        dc, feats, meta, total, g1);
    fill_kernel<<<(N_EDGES / 4 + 255) / 256, 256, 0, stream>>>(
        src, dst, rank, (const int*)meta, csr_src);
    gemm_kernel<<<(N_NODES + 31) / 32, 256, 0, stream>>>(feats, w0, out);

    // cols 64..127 = (norm ⊙ A g1) @ W1, saving g2 = bf16(norm² ⊙ A g1)
    spmm_gemm<1><<<4096, 256, 0, stream>>>(
        g1, meta, csr_src, w1, g2, out, 64);
    // cols 128..191 = (norm ⊙ A g2) @ W2
    spmm_gemm<0><<<4096, 256, 0, stream>>>(
        g2, meta, csr_src, w2, nullptr, out, 128);
}

// Round 8
// 342.437 us; speedup vs baseline: 1.8431x; 1.0881x over previous
//
#include <hip/hip_runtime.h>
#include <hip/hip_bf16.h>

#define N_NODES 100000
#define N_EDGES 1000000
#define D 64

// ---- histogram: ONE packed 64-bit atomic per edge, 4 edges/thread --------
// bits [63:40] = edge count, bits [39:0] = fixed-point sum of (w + 8) * 2^20
// The atomic's RETURN gives this edge's rank within its dst row -> rank[]
// so the CSR fill needs NO atomics.
__global__ __launch_bounds__(256) void hist_kernel(
    const int* __restrict__ dst, const int* __restrict__ efeat,
    const float* __restrict__ edge_weight,
    unsigned long long* __restrict__ dc,
    unsigned char* __restrict__ rank) {
    int e0 = (blockIdx.x * 256 + threadIdx.x) * 4;
    if (e0 >= N_EDGES) return;                 // N_EDGES % 4 == 0
    int4 d4 = *(const int4*)(dst + e0);
    int4 t4 = *(const int4*)(efeat + e0);
    float w0 = edge_weight[t4.x - 1] * 10.0f;
    float w1 = edge_weight[t4.y - 1] * 10.0f;
    float w2 = edge_weight[t4.z - 1] * 10.0f;
    float w3 = edge_weight[t4.w - 1] * 10.0f;
    w0 = w0 > 0.0f ? w0 : 0.01f * w0;          // leaky_relu, slope 0.01
    w1 = w1 > 0.0f ? w1 : 0.01f * w1;
    w2 = w2 > 0.0f ? w2 : 0.01f * w2;
    w3 = w3 > 0.0f ? w3 : 0.01f * w3;
    unsigned long long f0 = (unsigned long long)__float2uint_rn((w0 + 8.0f) * 1048576.0f);
    unsigned long long f1 = (unsigned long long)__float2uint_rn((w1 + 8.0f) * 1048576.0f);
    unsigned long long f2 = (unsigned long long)__float2uint_rn((w2 + 8.0f) * 1048576.0f);
    unsigned long long f3 = (unsigned long long)__float2uint_rn((w3 + 8.0f) * 1048576.0f);
    unsigned long long o0 = atomicAdd(&dc[d4.x], (1ull << 40) | f0);
    unsigned long long o1 = atomicAdd(&dc[d4.y], (1ull << 40) | f1);
    unsigned long long o2 = atomicAdd(&dc[d4.z], (1ull << 40) | f2);
    unsigned long long o3 = atomicAdd(&dc[d4.w], (1ull << 40) | f3);
    uchar4 r;
    r.x = (unsigned char)(o0 >> 40);
    r.y = (unsigned char)(o1 >> 40);
    r.z = (unsigned char)(o2 >> 40);
    r.w = (unsigned char)(o3 >> 40);
    *(uchar4*)(rank + e0) = r;
}

// ---- fused: dc -> meta{row_start,cnt,norm}, CSR alloc, AND build g1 ------
__global__ __launch_bounds__(256) void alloc_prep_kernel(
    const unsigned long long* __restrict__ dc,
    const float* __restrict__ feats,
    int4* __restrict__ meta,
    int* __restrict__ total,
    __hip_bfloat16* __restrict__ g1) {
    __shared__ int lds[256];
    __shared__ float norm_s[256];
    __shared__ int base_s;
    const int tid = threadIdx.x;
    const int i = blockIdx.x * 256 + tid;
    int v = 0;
    float nv = 1.0f;
    if (i < N_NODES) {
        unsigned long long p = dc[i];
        v = (int)(p >> 40);
        float deg = (float)(p & ((1ull << 40) - 1)) * (1.0f / 1048576.0f)
                    - 8.0f * (float)v;
        deg = deg < 1.0f ? 1.0f : deg;
        nv = rsqrtf(deg);
    }
    norm_s[tid] = nv;
    lds[tid] = v;
    __syncthreads();
    for (int off = 1; off < 256; off <<= 1) {
        int add = (tid >= off) ? lds[tid - off] : 0;
        __syncthreads();
        lds[tid] += add;
        __syncthreads();
    }
    if (tid == 255) base_s = atomicAdd(total, lds[255]);
    __syncthreads();
    if (i < N_NODES) {
        int4 m;
        m.x = base_s + lds[tid] - v;       // row_start (block-excl + base)
        m.y = v;                           // cnt
        m.z = __float_as_int(nv);          // norm
        m.w = 0;
        meta[i] = m;
    }
    // ---- g1[n][k] = bf16(feats[n][k] * norm[n]) for this block's nodes ---
    const float4* f4 = (const float4*)feats;
    __hip_bfloat162* g1p = (__hip_bfloat162*)g1;
    const int base4 = blockIdx.x * 4096;   // 256 nodes * 16 float4/node
#pragma unroll
    for (int r = 0; r < 16; r++) {
        int li = r * 256 + tid;
        int gi = base4 + li;
        if (gi < N_NODES * 16) {
            float4 vv = f4[gi];
            float ns = norm_s[li >> 4];
            __hip_bfloat162 a, b;
            a.x = __float2bfloat16(vv.x * ns); a.y = __float2bfloat16(vv.y * ns);
            b.x = __float2bfloat16(vv.z * ns); b.y = __float2bfloat16(vv.w * ns);
            g1p[gi * 2]     = a;
            g1p[gi * 2 + 1] = b;
        }
    }
}

// ---- atomic-free CSR fill: pos = row_start[dst] + rank, 4 edges/thread ---
__global__ __launch_bounds__(256) void fill_kernel(
    const int* __restrict__ src, const int* __restrict__ dst,
    const unsigned char* __restrict__ rank,
    const int* __restrict__ meta_i,        // meta as int*, row_start at 4*d
    int* __restrict__ csr_src) {
    int e0 = (blockIdx.x * 256 + threadIdx.x) * 4;
    if (e0 >= N_EDGES) return;
    int4 d4 = *(const int4*)(dst + e0);
    uchar4 r4 = *(const uchar4*)(rank + e0);
    int4 s4 = *(const int4*)(src + e0);
    int p0 = meta_i[d4.x * 4] + r4.x;          // 4 independent random reads
    int p1 = meta_i[d4.y * 4] + r4.y;
    int p2 = meta_i[d4.z * 4] + r4.z;
    int p3 = meta_i[d4.w * 4] + r4.w;
    csr_src[p0] = s4.x;
    csr_src[p1] = s4.y;
    csr_src[p2] = s4.z;
    csr_src[p3] = s4.w;
}

// ---- plain GEMM for j=0: out[:,0:64] = feats @ W0 ----
__global__ __launch_bounds__(256) void gemm_kernel(
    const float* __restrict__ H,
    const float* __restrict__ W,
    float* __restrict__ out) {
    __shared__ float wt[D][D];
    __shared__ float ht[32][D];
    const int tid = threadIdx.x;
    const int node0 = blockIdx.x * 32;
    for (int i = tid; i < D * D; i += 256)
        ((float*)wt)[i] = W[i];
    for (int i = tid; i < 32 * D; i += 256) {
        int n = i >> 6;
        int k = i & 63;
        int node = node0 + n;
        ht[n][k] = (node < N_NODES) ? H[(size_t)node * D + k] : 0.0f;
    }
    __syncthreads();
    const int col = tid & 63;
    const int nb = tid >> 6;
    float acc[8];
#pragma unroll
    for (int r = 0; r < 8; r++) acc[r] = 0.0f;
    for (int k = 0; k < D; k++) {
        float wv = wt[k][col];
#pragma unroll
        for (int r = 0; r < 8; r++)
            acc[r] += ht[nb * 8 + r][k] * wv;
    }
#pragma unroll
    for (int r = 0; r < 8; r++) {
        int node = node0 + nb * 8 + r;
        if (node < N_NODES)
            out[(size_t)node * 192 + col] = acc[r];
    }
}

// ---- fused bf16 gather-sum + GEMM epilogue, pipelined persistent waves ---
// Round-6 structure (correctness-verified) at NATURAL register allocation:
// round 6's 215 us was __launch_bounds__(256,8) forcing VGPR 48->32 and
// spilling (FETCH 103->635 MB scratch). No waves-per-EU floor here.
//  * coalesced index load: lane l holds csr index of edge l (one instr/row)
//  * wave-UNIFORM shfl bounds (exec-mask rule: shfl from exec-off lane is
//    undefined; all shfls at full exec, only gathers predicated)
//  * 2-deep cross-node prefetch: meta[n+2s], idx[n+s] fly under n's gathers
template <int SAVE_G2>
__global__ __launch_bounds__(256) void spmm_gemm(
    const __hip_bfloat16* __restrict__ G,
    const int4* __restrict__ meta,
    const int* __restrict__ csr_src,
    const float* __restrict__ W,
    __hip_bfloat16* __restrict__ g2,
    float* __restrict__ out, int col_off) {
    __shared__ float wt[D * D];               // wt[k*D + col]
    const int tid = threadIdx.x;
    for (int i = tid; i < D * D; i += 256) wt[i] = W[i];
    __syncthreads();                          // once per block

    const int wv = tid >> 6;
    const int lane = tid & 63;
    const int half = lane >> 5;               // edge parity
    const int fp = lane & 31;                 // feature-pair index
    const unsigned int* Gp = (const unsigned int*)G;   // row = 32 dwords
    const int stride = gridDim.x * 4;

    const int n0 = blockIdx.x * 4 + wv;
    if (n0 >= N_NODES) return;                // uniform per wave; after barrier

    // pipeline prologue
    int4 m0 = meta[n0];
    int nn1 = n0 + stride;
    int4 m1 = meta[nn1 < N_NODES ? nn1 : n0];         // clamped; unused if OOB
    int idx0 = csr_src[m0.x + (lane < m0.y ? lane : 0)];

    for (int node = n0; node < N_NODES; node += stride) {
        // prefetches for the pipeline (fly under this node's gathers)
        int nn2 = node + 2 * stride;
        int4 m2 = meta[nn2 < N_NODES ? nn2 : node];
        int idx1 = csr_src[m1.x + (lane < m1.y ? lane : 0)];

        const int cnt = m0.y;
        const float nn = __int_as_float(m0.z);
        const int jmax = cnt < 64 ? cnt : 64;
        const int full = jmax & ~7;           // complete 8-slot groups

        float accx = 0.0f, accy = 0.0f;
        // main loop: UNIFORM bound -> exec full at every shfl
        for (int base = 0; base < full; base += 8) {
            int j0 = base + half;
            int s0 = __shfl(idx0, j0);
            int s1 = __shfl(idx0, j0 + 2);
            int s2 = __shfl(idx0, j0 + 4);
            int s3 = __shfl(idx0, j0 + 6);
            unsigned int p0 = Gp[(size_t)s0 * 32 + fp];
            unsigned int p1 = Gp[(size_t)s1 * 32 + fp];
            unsigned int p2 = Gp[(size_t)s2 * 32 + fp];
            unsigned int p3 = Gp[(size_t)s3 * 32 + fp];
            float x0 = __uint_as_float(p0 << 16) + __uint_as_float(p1 << 16);
            float x1 = __uint_as_float(p2 << 16) + __uint_as_float(p3 << 16);
            float y0 = __uint_as_float(p0 & 0xffff0000u) + __uint_as_float(p1 & 0xffff0000u);
            float y1 = __uint_as_float(p2 & 0xffff0000u) + __uint_as_float(p3 & 0xffff0000u);
            accx += x0 + x1;
            accy += y0 + y1;
        }
        // remainder group: condition wave-UNIFORM, shfls at full exec;
        // only the gathers are per-lane predicated.
        if (full < jmax) {
            int j0 = full + half;
            int s0 = __shfl(idx0, j0);
            int s1 = __shfl(idx0, j0 + 2);
            int s2 = __shfl(idx0, j0 + 4);
            int s3 = __shfl(idx0, j0 + 6);
            if (j0 < jmax) {
                unsigned int p = Gp[(size_t)s0 * 32 + fp];
                accx += __uint_as_float(p << 16);
                accy += __uint_as_float(p & 0xffff0000u);
            }
            if (j0 + 2 < jmax) {
                unsigned int p = Gp[(size_t)s1 * 32 + fp];
                accx += __uint_as_float(p << 16);
                accy += __uint_as_float(p & 0xffff0000u);
            }
            if (j0 + 4 < jmax) {
                unsigned int p = Gp[(size_t)s2 * 32 + fp];
                accx += __uint_as_float(p << 16);
                accy += __uint_as_float(p & 0xffff0000u);
            }
            if (j0 + 6 < jmax) {
                unsigned int p = Gp[(size_t)s3 * 32 + fp];
                accx += __uint_as_float(p << 16);
                accy += __uint_as_float(p & 0xffff0000u);
            }
        }
        // deg > 64 fallback (practically never): broadcast loads, NO shfl
        for (int j = 64 + half; j < cnt; j += 2) {
            unsigned int p = Gp[(size_t)csr_src[m0.x + j] * 32 + fp];
            accx += __uint_as_float(p << 16);
            accy += __uint_as_float(p & 0xffff0000u);
        }

        // combine halves: lane l and l^32 hold the same feature pair
        accx += __shfl_xor(accx, 32);
        accy += __shfl_xor(accy, 32);
        accx *= nn;                           // dst-side norm folded here
        accy *= nn;

        if (SAVE_G2 && half == 0) {
            __hip_bfloat162 hb;
            hb.x = __float2bfloat16(accx * nn);
            hb.y = __float2bfloat16(accy * nn);
            ((__hip_bfloat162*)g2)[(size_t)node * 32 + fp] = hb;
        }

        // epilogue: o[col] = sum_k h[k]*W[k][col]; h[2q],h[2q+1] from lane q
        float o0 = 0.0f, o1 = 0.0f;
#pragma unroll
        for (int q = 0; q < 32; q++) {
            float hx = __uint_as_float(
                __builtin_amdgcn_readlane(__float_as_uint(accx), q));
            float hy = __uint_as_float(
                __builtin_amdgcn_readlane(__float_as_uint(accy), q));
            o0 = fmaf(hx, wt[(2 * q) * D + lane], o0);
            o1 = fmaf(hy, wt[(2 * q + 1) * D + lane], o1);
        }
        out[(size_t)node * 192 + col_off + lane] = o0 + o1;

        // pipeline shift
        m0 = m1; m1 = m2; idx0 = idx1;
    }
}

extern "C" void kernel_launch(void* const* d_in, const int* in_sizes, int n_in,
                              void* d_out, int out_size, void* d_ws, size_t ws_size,
                              hipStream_t stream) {
    const float* feats = (const float*)d_in[0];
    const float* ew    = (const float*)d_in[1];
    const float* w0    = (const float*)d_in[2];
    const float* w1    = (const float*)d_in[3];
    const float* w2    = (const float*)d_in[4];
    const int* src   = (const int*)d_in[5];
    const int* dst   = (const int*)d_in[6];
    const int* efeat = (const int*)d_in[7];
    float* out = (float*)d_out;

    // ws layout (~32 MiB): dc[N] u64 (800000 B) | total (16 B) |
    // meta[N] int4 (1.6 MB) | csr_src[1M] (4 MB) | g1 (12.8 MB) | g2 (12.8 MB)
    // rank[1M u8] ALIASES g2: hist writes rank, fill reads it, then spmm<1>
    // overwrites g2 — strictly ordered on the stream.
    unsigned long long* dc = (unsigned long long*)d_ws;
    int* total     = (int*)(dc + N_NODES);
    int4* meta     = (int4*)((char*)total + 16);
    int* csr_src   = (int*)(meta + N_NODES);
    __hip_bfloat16* g1 = (__hip_bfloat16*)(csr_src + N_EDGES);
    __hip_bfloat16* g2 = g1 + (size_t)N_NODES * D;
    unsigned char* rank = (unsigned char*)g2;  // dead before spmm<1> runs

    // zero dc + total only (~800 KB)
    hipMemsetAsync(d_ws, 0, sizeof(unsigned long long) * N_NODES + 16, stream);

    hist_kernel<<<(N_EDGES / 4 + 255) / 256, 256, 0, stream>>>(
        dst, efeat, ew, dc, rank);
    alloc_prep_kernel<<<(N_NODES + 255) / 256, 256, 0, stream>>>(
        dc, feats, meta, total, g1);
    fill_kernel<<<(N_EDGES / 4 + 255) / 256, 256, 0, stream>>>(
        src, dst, rank, (const int*)meta, csr_src);
    gemm_kernel<<<(N_NODES + 31) / 32, 256, 0, stream>>>(feats, w0, out);

    // cols 64..127 = (norm ⊙ A g1) @ W1, saving g2 = bf16(norm² ⊙ A g1)
    spmm_gemm<1><<<4096, 256, 0, stream>>>(
        g1, meta, csr_src, w1, g2, out, 64);
    // cols 128..191 = (norm ⊙ A g2) @ W2
    spmm_gemm<0><<<4096, 256, 0, stream>>>(
        g2, meta, csr_src, w2, nullptr, out, 128);
}